// Round 5
// baseline (774.150 us; speedup 1.0000x reference)
//
#include <hip/hip_runtime.h>
#include <hip/hip_bf16.h>
#include <math.h>

// Only rows (b, n==0) reach output slice [:,0,-1,:] -> 4 independent sequences
// of 64 positions. 8 launches: per layer K_A (32 wgs x 256) and K_BS (4 wgs x
// 1024, conv + x_proj + dt + scan LDS-resident). R4 post-mortem: both kernels
// were latency-bound on streamed global weights (kbs 131us at 31% VALU on its
// CUs). This round: explicit double-buffered weight prefetch everywhere + K-split
// mapping in kbs x_proj.

// Workspace layout (float offsets), 256 compact rows r = s*64 + l
#define WS_RESIDUAL 0          // [256][128]
#define WS_XZ       32768      // [256][512] cols 0..255 = xc, 256..511 = z
#define WS_Y        163840     // [256][256]

__device__ __forceinline__ float silu_f(float v) {
    return v / (1.0f + __expf(-v));
}

// ---------------------------------------------------------------------------
// K_A: [layer 0: full MLP] or [layer>0: gate + out_proj(prev)] + residual
//      + rmsnorm + in_proj.  32 wgs x 256 thr, 8 rows per wg.
// ---------------------------------------------------------------------------
__global__ __launch_bounds__(256, 1) void ka_kernel(
    const float* __restrict__ mha_in,
    const float* __restrict__ mlp_w1, const float* __restrict__ mlp_b1,
    const float* __restrict__ mlp_w2, const float* __restrict__ mlp_b2,
    const float* __restrict__ in_proj_w, const float* __restrict__ out_proj_w,
    const float* __restrict__ blk_norm_w,
    float* __restrict__ ws, int layer)
{
    float* residual = ws + WS_RESIDUAL;
    float* xz       = ws + WS_XZ;
    float* ybuf     = ws + WS_Y;

    __shared__ float gated[8][256];   // layer0: cols 0..127 = x, 128..255 = h1
    __shared__ float res[8][128];
    __shared__ float hn[8][128];
    __shared__ float part[8][32];
    __shared__ float scale[8];

    const int tid  = threadIdx.x;
    const int row0 = blockIdx.x * 8;

    if (layer == 0) {
        for (int idx = tid; idx < 8*128; idx += 256) {
            int i = idx >> 7, c = idx & 127;
            int r = row0 + i; int s = r >> 6, l = r & 63;
            gated[i][c] = mha_in[(s*4096 + l)*128 + c];
        }
        __syncthreads();
        {   // h1 = gelu(x @ w1^T + b1), K=128, batch-4 double-buffered prefetch
            int jg = tid & 63, rq = tid >> 6;
            int j0 = jg*2;
            const float* W0 = &mlp_w1[(size_t)(j0  )*128];
            const float* W1 = &mlp_w1[(size_t)(j0+1)*128];
            float4 a0[4], a1[4], b0[4], b1[4];
            #pragma unroll
            for (int i = 0; i < 4; ++i) {
                a0[i] = *(const float4*)&W0[i*4];
                a1[i] = *(const float4*)&W1[i*4];
            }
            float acc[2][2] = {{0.f,0.f},{0.f,0.f}};
            #pragma unroll
            for (int b = 0; b < 8; ++b) {
                if (b < 7) {
                    #pragma unroll
                    for (int i = 0; i < 4; ++i) {
                        b0[i] = *(const float4*)&W0[(b+1)*16 + i*4];
                        b1[i] = *(const float4*)&W1[(b+1)*16 + i*4];
                    }
                }
                #pragma unroll
                for (int i = 0; i < 4; ++i) {
                    int k4 = b*4 + i;
                    #pragma unroll
                    for (int rr = 0; rr < 2; ++rr) {
                        float4 xv = *(const float4*)&gated[rq*2+rr][k4*4];
                        acc[rr][0] += xv.x*a0[i].x + xv.y*a0[i].y + xv.z*a0[i].z + xv.w*a0[i].w;
                        acc[rr][1] += xv.x*a1[i].x + xv.y*a1[i].y + xv.z*a1[i].z + xv.w*a1[i].w;
                    }
                }
                #pragma unroll
                for (int i = 0; i < 4; ++i) { a0[i] = b0[i]; a1[i] = b1[i]; }
            }
            __syncthreads();
            #pragma unroll
            for (int rr = 0; rr < 2; ++rr)
                #pragma unroll
                for (int jj = 0; jj < 2; ++jj) {
                    float v = acc[rr][jj] + mlp_b1[j0+jj];
                    gated[rq*2+rr][128 + j0 + jj] = 0.5f*v*(1.0f + erff(v*0.70710678118f));
                }
        }
        __syncthreads();
        {   // h2 = h1 @ w2^T + b2, K=128, same prefetch
            int jg = tid & 63, rq = tid >> 6;
            int j0 = jg*2;
            const float* W0 = &mlp_w2[(size_t)(j0  )*128];
            const float* W1 = &mlp_w2[(size_t)(j0+1)*128];
            float4 a0[4], a1[4], b0[4], b1[4];
            #pragma unroll
            for (int i = 0; i < 4; ++i) {
                a0[i] = *(const float4*)&W0[i*4];
                a1[i] = *(const float4*)&W1[i*4];
            }
            float acc[2][2] = {{0.f,0.f},{0.f,0.f}};
            #pragma unroll
            for (int b = 0; b < 8; ++b) {
                if (b < 7) {
                    #pragma unroll
                    for (int i = 0; i < 4; ++i) {
                        b0[i] = *(const float4*)&W0[(b+1)*16 + i*4];
                        b1[i] = *(const float4*)&W1[(b+1)*16 + i*4];
                    }
                }
                #pragma unroll
                for (int i = 0; i < 4; ++i) {
                    int k4 = b*4 + i;
                    #pragma unroll
                    for (int rr = 0; rr < 2; ++rr) {
                        float4 xv = *(const float4*)&gated[rq*2+rr][128 + k4*4];
                        acc[rr][0] += xv.x*a0[i].x + xv.y*a0[i].y + xv.z*a0[i].z + xv.w*a0[i].w;
                        acc[rr][1] += xv.x*a1[i].x + xv.y*a1[i].y + xv.z*a1[i].z + xv.w*a1[i].w;
                    }
                }
                #pragma unroll
                for (int i = 0; i < 4; ++i) { a0[i] = b0[i]; a1[i] = b1[i]; }
            }
            #pragma unroll
            for (int rr = 0; rr < 2; ++rr) {
                int i = rq*2 + rr, r = row0 + i;
                #pragma unroll
                for (int jj = 0; jj < 2; ++jj) {
                    float v = acc[rr][jj] + mlp_b2[j0+jj];
                    res[i][j0+jj] = v;
                    residual[r*128 + j0 + jj] = v;
                }
            }
        }
    } else {
        for (int idx = tid; idx < 8*256; idx += 256) {
            int i = idx >> 8, dd = idx & 255;
            int r = row0 + i;
            float yv = ybuf[r*256 + dd];
            float zv = xz[r*512 + 256 + dd];
            gated[i][dd] = yv * silu_f(zv);
        }
        __syncthreads();
        {   // out_proj: 2 cols, K=256, batch-8 double-buffered prefetch
            const float* ow = out_proj_w + (size_t)(layer-1)*128*256;
            int jg = tid & 63, rq = tid >> 6;
            int j0 = jg*2;
            const float* W0 = &ow[(size_t)(j0  )*256];
            const float* W1 = &ow[(size_t)(j0+1)*256];
            float4 a0[8], a1[8], b0[8], b1[8];
            #pragma unroll
            for (int i = 0; i < 8; ++i) {
                a0[i] = *(const float4*)&W0[i*4];
                a1[i] = *(const float4*)&W1[i*4];
            }
            float acc[2][2] = {{0.f,0.f},{0.f,0.f}};
            #pragma unroll
            for (int b = 0; b < 8; ++b) {
                if (b < 7) {
                    #pragma unroll
                    for (int i = 0; i < 8; ++i) {
                        b0[i] = *(const float4*)&W0[(b+1)*32 + i*4];
                        b1[i] = *(const float4*)&W1[(b+1)*32 + i*4];
                    }
                }
                #pragma unroll
                for (int i = 0; i < 8; ++i) {
                    int k4 = b*8 + i;
                    #pragma unroll
                    for (int rr = 0; rr < 2; ++rr) {
                        float4 xv = *(const float4*)&gated[rq*2+rr][k4*4];
                        acc[rr][0] += xv.x*a0[i].x + xv.y*a0[i].y + xv.z*a0[i].z + xv.w*a0[i].w;
                        acc[rr][1] += xv.x*a1[i].x + xv.y*a1[i].y + xv.z*a1[i].z + xv.w*a1[i].w;
                    }
                }
                #pragma unroll
                for (int i = 0; i < 8; ++i) { a0[i] = b0[i]; a1[i] = b1[i]; }
            }
            #pragma unroll
            for (int rr = 0; rr < 2; ++rr) {
                int i = rq*2 + rr, r = row0 + i;
                #pragma unroll
                for (int jj = 0; jj < 2; ++jj) {
                    float v = acc[rr][jj] + residual[r*128 + j0 + jj];
                    res[i][j0+jj] = v;
                    residual[r*128 + j0 + jj] = v;
                }
            }
        }
    }
    __syncthreads();

    // rmsnorm
    {
        int r = tid >> 5, lane = tid & 31;
        float sq = 0.f;
        #pragma unroll
        for (int t = 0; t < 4; ++t) { float v = res[r][lane + 32*t]; sq += v*v; }
        part[r][lane] = sq;
    }
    __syncthreads();
    if (tid < 8) {
        float sq = 0.f;
        #pragma unroll
        for (int t = 0; t < 32; ++t) sq += part[tid][t];
        scale[tid] = rsqrtf(sq * (1.0f/128.0f) + 1e-5f);
    }
    __syncthreads();
    {
        const float* bw = blk_norm_w + layer*128;
        for (int idx = tid; idx < 8*128; idx += 256) {
            int i = idx >> 7, c = idx & 127;
            hn[i][c] = res[i][c] * scale[i] * bw[c];
        }
    }
    __syncthreads();

    // in_proj: 4 cols x 4 rows, K=128, batch-4 double-buffered prefetch
    {
        const float* iw = in_proj_w + (size_t)layer*512*128;
        int jg = tid & 127, rh = tid >> 7;
        int j0 = jg*4;
        const float* Wp0 = &iw[(size_t)(j0  )*128];
        const float* Wp1 = &iw[(size_t)(j0+1)*128];
        const float* Wp2 = &iw[(size_t)(j0+2)*128];
        const float* Wp3 = &iw[(size_t)(j0+3)*128];
        float4 wa[4][4], wb[4][4];   // [j][i]
        #pragma unroll
        for (int i = 0; i < 4; ++i) {
            wa[0][i] = *(const float4*)&Wp0[i*4];
            wa[1][i] = *(const float4*)&Wp1[i*4];
            wa[2][i] = *(const float4*)&Wp2[i*4];
            wa[3][i] = *(const float4*)&Wp3[i*4];
        }
        float acc[4][4] = {};
        #pragma unroll
        for (int b = 0; b < 8; ++b) {
            if (b < 7) {
                #pragma unroll
                for (int i = 0; i < 4; ++i) {
                    wb[0][i] = *(const float4*)&Wp0[(b+1)*16 + i*4];
                    wb[1][i] = *(const float4*)&Wp1[(b+1)*16 + i*4];
                    wb[2][i] = *(const float4*)&Wp2[(b+1)*16 + i*4];
                    wb[3][i] = *(const float4*)&Wp3[(b+1)*16 + i*4];
                }
            }
            #pragma unroll
            for (int i = 0; i < 4; ++i) {
                int k4 = b*4 + i;
                #pragma unroll
                for (int rr = 0; rr < 4; ++rr) {
                    float4 xv = *(const float4*)&hn[rh*4+rr][k4*4];
                    #pragma unroll
                    for (int jj = 0; jj < 4; ++jj)
                        acc[rr][jj] += xv.x*wa[jj][i].x + xv.y*wa[jj][i].y
                                     + xv.z*wa[jj][i].z + xv.w*wa[jj][i].w;
                }
            }
            #pragma unroll
            for (int jj = 0; jj < 4; ++jj)
                #pragma unroll
                for (int i = 0; i < 4; ++i) wa[jj][i] = wb[jj][i];
        }
        #pragma unroll
        for (int rr = 0; rr < 4; ++rr) {
            int r = row0 + rh*4 + rr;
            float4 o; o.x = acc[rr][0]; o.y = acc[rr][1]; o.z = acc[rr][2]; o.w = acc[rr][3];
            *(float4*)&xz[r*512 + j0] = o;
        }
    }
}

// ---------------------------------------------------------------------------
// K_BS: conv + silu + x_proj + dt + selective scan, LDS-resident.
// 4 wgs x 1024 thr, one sequence each. do_fin: fold in final epilogue.
// ---------------------------------------------------------------------------
__global__ __launch_bounds__(1024) void kbs_kernel(
    const float* __restrict__ conv_w, const float* __restrict__ conv_b,
    const float* __restrict__ x_proj_w,
    const float* __restrict__ dt_proj_w, const float* __restrict__ dt_proj_b,
    const float* __restrict__ A_log, const float* __restrict__ D_skip,
    const float* __restrict__ out_proj_w, const float* __restrict__ norm_f_w,
    const int* __restrict__ mask,
    float* __restrict__ ws, float* __restrict__ out, int layer, int do_fin)
{
    __shared__ float uS[64][260];    // stride 260 -> conflict-free b128 row reads
    __shared__ float dtS[64][256];
    __shared__ float xdbl[64][44];   // 0..7 dt-pre, 8..23 B, 24..39 C
    __shared__ float fing[256];
    __shared__ float finpart[4][128];
    __shared__ float finred[2];
    __shared__ float validf;

    float* residual = ws + WS_RESIDUAL;
    float* xz       = ws + WS_XZ;
    float* ybuf     = ws + WS_Y;

    const int tid  = threadIdx.x;
    const int s    = blockIdx.x;
    const int base = s * 64;

    // ---- causal conv (width 4) + silu -> uS; loads batched into registers ----
    {
        const int d = tid & 255;
        const int lbase = (tid >> 8) * 16;
        const float* cw = conv_w + (size_t)(layer*256 + d)*4;
        float w0 = cw[0], w1 = cw[1], w2 = cw[2], w3 = cw[3];
        float cb = conv_b[layer*256 + d];
        float xm3 = (lbase >= 3) ? xz[(size_t)(base + lbase - 3)*512 + d] : 0.f;
        float xm2 = (lbase >= 2) ? xz[(size_t)(base + lbase - 2)*512 + d] : 0.f;
        float xm1 = (lbase >= 1) ? xz[(size_t)(base + lbase - 1)*512 + d] : 0.f;
        float xv[16];
        #pragma unroll
        for (int i = 0; i < 16; ++i)
            xv[i] = xz[(size_t)(base + lbase + i)*512 + d];
        #pragma unroll
        for (int i = 0; i < 16; ++i) {
            float v = cb + w0*xm3 + w1*xm2 + w2*xm1 + w3*xv[i];
            uS[lbase + i][d] = silu_f(v);
            xm3 = xm2; xm2 = xm1; xm1 = xv[i];
        }
    }
    __syncthreads();

    // ---- x_proj: 4 rows x 4 cols x 4-way K-split per thread ------------------
    // wave w -> rows w*4..w*4+3; lane: t=lane&15 (col-block, t<10), rq=lane>>4
    // (K subset k4 = kk*4+rq). Weights double-buffered from global (L2-hot).
    {
        const int lane = tid & 63, wavei = tid >> 6;
        const int t = lane & 15, rq = lane >> 4;
        const int rbase = wavei * 4;
        const float* xw = x_proj_w + (size_t)layer*40*256;
        const int c0 = t * 4;
        float acc[4][4] = {};
        if (t < 10) {
            const float* Wp0 = &xw[(size_t)(c0  )*256];
            const float* Wp1 = &xw[(size_t)(c0+1)*256];
            const float* Wp2 = &xw[(size_t)(c0+2)*256];
            const float* Wp3 = &xw[(size_t)(c0+3)*256];
            float4 wcur[4], wnxt[4];
            {
                int k4 = rq;
                wcur[0] = *(const float4*)&Wp0[k4*4];
                wcur[1] = *(const float4*)&Wp1[k4*4];
                wcur[2] = *(const float4*)&Wp2[k4*4];
                wcur[3] = *(const float4*)&Wp3[k4*4];
            }
            #pragma unroll
            for (int kk = 0; kk < 16; ++kk) {
                int k4c = kk*4 + rq;
                if (kk < 15) {
                    int k4n = (kk+1)*4 + rq;
                    wnxt[0] = *(const float4*)&Wp0[k4n*4];
                    wnxt[1] = *(const float4*)&Wp1[k4n*4];
                    wnxt[2] = *(const float4*)&Wp2[k4n*4];
                    wnxt[3] = *(const float4*)&Wp3[k4n*4];
                }
                float4 u[4];
                #pragma unroll
                for (int rr = 0; rr < 4; ++rr)
                    u[rr] = *(const float4*)&uS[rbase+rr][k4c*4];
                #pragma unroll
                for (int rr = 0; rr < 4; ++rr)
                    #pragma unroll
                    for (int j = 0; j < 4; ++j)
                        acc[rr][j] += u[rr].x*wcur[j].x + u[rr].y*wcur[j].y
                                    + u[rr].z*wcur[j].z + u[rr].w*wcur[j].w;
                #pragma unroll
                for (int j = 0; j < 4; ++j) wcur[j] = wnxt[j];
            }
        }
        // reduce across rq (lane bits 4,5)
        #pragma unroll
        for (int rr = 0; rr < 4; ++rr)
            #pragma unroll
            for (int j = 0; j < 4; ++j) {
                float v = acc[rr][j];
                v += __shfl_xor(v, 16);
                v += __shfl_xor(v, 32);
                if (rq == 0 && t < 10) xdbl[rbase+rr][c0+j] = v;
            }
    }
    __syncthreads();

    // ---- dt = softplus(xdbl[:,:8] @ dtw^T + dtb) -> dtS ----
    {
        const int d = tid & 255;
        const int lbase = (tid >> 8) * 16;
        const float* dw = dt_proj_w + (size_t)(layer*256 + d)*8;
        float w[8];
        #pragma unroll
        for (int t = 0; t < 8; ++t) w[t] = dw[t];
        float bdt = dt_proj_b[layer*256 + d];
        #pragma unroll
        for (int i = 0; i < 16; ++i) {
            int l = lbase + i;
            float pre = bdt;
            #pragma unroll
            for (int t = 0; t < 8; ++t) pre += xdbl[l][t]*w[t];
            dtS[l][d] = (pre > 20.f) ? pre : log1pf(__expf(pre));
        }
    }
    __syncthreads();

    // ---- selective scan: 4 threads per channel, 4 states each, LDS operands --
    {
        const int d = tid >> 2, sub = tid & 3;
        float A[4], h[4] = {0.f,0.f,0.f,0.f};
        #pragma unroll
        for (int j = 0; j < 4; ++j)
            A[j] = -__expf(A_log[(size_t)(layer*256 + d)*16 + sub*4 + j]);
        float Dsk = D_skip[layer*256 + d];

        float dtv = dtS[0][d];
        float uv  = uS[0][d];
        float4 B4 = *(const float4*)&xdbl[0][ 8 + sub*4];
        float4 C4 = *(const float4*)&xdbl[0][24 + sub*4];

        for (int l = 0; l < 64; ++l) {
            float dtn = 0.f, un = 0.f; float4 Bn = {0,0,0,0}, Cn = {0,0,0,0};
            if (l < 63) {
                dtn = dtS[l+1][d];
                un  = uS[l+1][d];
                Bn  = *(const float4*)&xdbl[l+1][ 8 + sub*4];
                Cn  = *(const float4*)&xdbl[l+1][24 + sub*4];
            }
            float du = dtv * uv;
            float yp = 0.f, dA;
            dA = __expf(dtv*A[0]); h[0] = dA*h[0] + du*B4.x; yp += h[0]*C4.x;
            dA = __expf(dtv*A[1]); h[1] = dA*h[1] + du*B4.y; yp += h[1]*C4.y;
            dA = __expf(dtv*A[2]); h[2] = dA*h[2] + du*B4.z; yp += h[2]*C4.z;
            dA = __expf(dtv*A[3]); h[3] = dA*h[3] + du*B4.w; yp += h[3]*C4.w;
            yp += __shfl_xor(yp, 1);
            yp += __shfl_xor(yp, 2);
            if (sub == 0) ybuf[(size_t)(base + l)*256 + d] = yp + uv*Dsk;
            dtv = dtn; uv = un; B4 = Bn; C4 = Cn;
        }
    }

    if (!do_fin) return;

    // ================= final epilogue: row l=63 only ==========================
    __syncthreads();
    if (tid < 256)
        fing[tid] = ybuf[(size_t)(base + 63)*256 + tid]
                  * silu_f(xz[(size_t)(base + 63)*512 + 256 + tid]);
    if (tid < 64) {
        unsigned long long b = __ballot(mask[s*4096 + tid] != 0);
        if (tid == 0) validf = (b != 0ULL) ? 1.f : 0.f;
    }
    __syncthreads();
    if (tid < 512) {
        int j = tid & 127, kh = tid >> 7;
        const float* ow = out_proj_w + (size_t)3*128*256 + (size_t)j*256;
        float acc = 0.f;
        for (int k4 = kh*16; k4 < kh*16 + 16; ++k4) {
            float4 g = *(const float4*)&fing[k4*4];
            float4 w = *(const float4*)&ow[k4*4];
            acc += g.x*w.x + g.y*w.y + g.z*w.z + g.w*w.w;
        }
        finpart[kh][j] = acc;
    }
    __syncthreads();
    float v = 0.f;
    if (tid < 128)
        v = finpart[0][tid] + finpart[1][tid] + finpart[2][tid] + finpart[3][tid]
          + residual[(size_t)(base + 63)*128 + tid];
    float p = v * v;
    p += __shfl_xor(p, 1);  p += __shfl_xor(p, 2);  p += __shfl_xor(p, 4);
    p += __shfl_xor(p, 8);  p += __shfl_xor(p, 16); p += __shfl_xor(p, 32);
    if (tid < 128 && (tid & 63) == 0) finred[tid >> 6] = p;
    __syncthreads();
    if (tid < 128) {
        float tot = finred[0] + finred[1];
        out[s*128 + tid] = v * rsqrtf(tot * (1.0f/128.0f) + 1e-5f)
                         * norm_f_w[tid] * validf;
    }
}

// ---------------------------------------------------------------------------
extern "C" void kernel_launch(void* const* d_in, const int* in_sizes, int n_in,
                              void* d_out, int out_size, void* d_ws, size_t ws_size,
                              hipStream_t stream) {
    const float* mha_in     = (const float*)d_in[0];
    const int*   mask       = (const int*)  d_in[1];
    const float* mlp_w1     = (const float*)d_in[2];
    const float* mlp_b1     = (const float*)d_in[3];
    const float* mlp_w2     = (const float*)d_in[4];
    const float* mlp_b2     = (const float*)d_in[5];
    const float* in_proj_w  = (const float*)d_in[6];
    const float* conv_w     = (const float*)d_in[7];
    const float* conv_b     = (const float*)d_in[8];
    const float* x_proj_w   = (const float*)d_in[9];
    const float* dt_proj_w  = (const float*)d_in[10];
    const float* dt_proj_b  = (const float*)d_in[11];
    const float* A_log      = (const float*)d_in[12];
    const float* D_skip     = (const float*)d_in[13];
    const float* out_proj_w = (const float*)d_in[14];
    const float* blk_norm_w = (const float*)d_in[15];
    const float* norm_f_w   = (const float*)d_in[16];
    float* ws  = (float*)d_ws;
    float* out = (float*)d_out;

    for (int layer = 0; layer < 4; ++layer) {
        ka_kernel<<<32, 256, 0, stream>>>(mha_in, mlp_w1, mlp_b1, mlp_w2, mlp_b2,
                                          in_proj_w, out_proj_w, blk_norm_w, ws, layer);
        kbs_kernel<<<4, 1024, 0, stream>>>(conv_w, conv_b, x_proj_w,
                                           dt_proj_w, dt_proj_b, A_log, D_skip,
                                           out_proj_w, norm_f_w, mask,
                                           ws, out, layer, (layer == 3) ? 1 : 0);
    }
}

// Round 6
// 709.794 us; speedup vs baseline: 1.0907x; 1.0907x over previous
//
#include <hip/hip_runtime.h>
#include <hip/hip_bf16.h>
#include <math.h>

// Only rows (b, n==0) reach output slice [:,0,-1,:] -> 4 independent sequences
// of 64 positions. 9 launches: per layer K_A (32 wgs x 256) + K_BS (16 wgs x
// 256: conv + x_proj redundant per wg, dt + scan for own 64 channels), then
// kfin. R5 post-mortem: 1024-thr blocks cap VGPRs at 64 -> prefetch spilled
// (FETCH 610KB->2.9MB). 256-thr blocks on 4x the CUs give full VGPR budget
// and 4x the per-CU miss capacity.

// Workspace layout (float offsets), 256 compact rows r = s*64 + l
#define WS_RESIDUAL 0          // [256][128]
#define WS_XZ       32768      // [256][512] cols 0..255 = xc, 256..511 = z
#define WS_Y        163840     // [256][256]

__device__ __forceinline__ float silu_f(float v) {
    return v / (1.0f + __expf(-v));
}

// ---------------------------------------------------------------------------
// K_A: [layer 0: full MLP] or [layer>0: gate + out_proj(prev)] + residual
//      + rmsnorm + in_proj.  32 wgs x 256 thr, 8 rows per wg.  (R5-proven)
// ---------------------------------------------------------------------------
__global__ __launch_bounds__(256, 1) void ka_kernel(
    const float* __restrict__ mha_in,
    const float* __restrict__ mlp_w1, const float* __restrict__ mlp_b1,
    const float* __restrict__ mlp_w2, const float* __restrict__ mlp_b2,
    const float* __restrict__ in_proj_w, const float* __restrict__ out_proj_w,
    const float* __restrict__ blk_norm_w,
    float* __restrict__ ws, int layer)
{
    float* residual = ws + WS_RESIDUAL;
    float* xz       = ws + WS_XZ;
    float* ybuf     = ws + WS_Y;

    __shared__ float gated[8][256];   // layer0: cols 0..127 = x, 128..255 = h1
    __shared__ float res[8][128];
    __shared__ float hn[8][128];
    __shared__ float part[8][32];
    __shared__ float scale[8];

    const int tid  = threadIdx.x;
    const int row0 = blockIdx.x * 8;

    if (layer == 0) {
        for (int idx = tid; idx < 8*128; idx += 256) {
            int i = idx >> 7, c = idx & 127;
            int r = row0 + i; int s = r >> 6, l = r & 63;
            gated[i][c] = mha_in[(s*4096 + l)*128 + c];
        }
        __syncthreads();
        {   // h1 = gelu(x @ w1^T + b1), K=128, batch-4 double-buffered prefetch
            int jg = tid & 63, rq = tid >> 6;
            int j0 = jg*2;
            const float* W0 = &mlp_w1[(size_t)(j0  )*128];
            const float* W1 = &mlp_w1[(size_t)(j0+1)*128];
            float4 a0[4], a1[4], b0[4], b1[4];
            #pragma unroll
            for (int i = 0; i < 4; ++i) {
                a0[i] = *(const float4*)&W0[i*4];
                a1[i] = *(const float4*)&W1[i*4];
            }
            float acc[2][2] = {{0.f,0.f},{0.f,0.f}};
            #pragma unroll
            for (int b = 0; b < 8; ++b) {
                if (b < 7) {
                    #pragma unroll
                    for (int i = 0; i < 4; ++i) {
                        b0[i] = *(const float4*)&W0[(b+1)*16 + i*4];
                        b1[i] = *(const float4*)&W1[(b+1)*16 + i*4];
                    }
                }
                #pragma unroll
                for (int i = 0; i < 4; ++i) {
                    int k4 = b*4 + i;
                    #pragma unroll
                    for (int rr = 0; rr < 2; ++rr) {
                        float4 xv = *(const float4*)&gated[rq*2+rr][k4*4];
                        acc[rr][0] += xv.x*a0[i].x + xv.y*a0[i].y + xv.z*a0[i].z + xv.w*a0[i].w;
                        acc[rr][1] += xv.x*a1[i].x + xv.y*a1[i].y + xv.z*a1[i].z + xv.w*a1[i].w;
                    }
                }
                #pragma unroll
                for (int i = 0; i < 4; ++i) { a0[i] = b0[i]; a1[i] = b1[i]; }
            }
            __syncthreads();
            #pragma unroll
            for (int rr = 0; rr < 2; ++rr)
                #pragma unroll
                for (int jj = 0; jj < 2; ++jj) {
                    float v = acc[rr][jj] + mlp_b1[j0+jj];
                    gated[rq*2+rr][128 + j0 + jj] = 0.5f*v*(1.0f + erff(v*0.70710678118f));
                }
        }
        __syncthreads();
        {   // h2 = h1 @ w2^T + b2, K=128, same prefetch
            int jg = tid & 63, rq = tid >> 6;
            int j0 = jg*2;
            const float* W0 = &mlp_w2[(size_t)(j0  )*128];
            const float* W1 = &mlp_w2[(size_t)(j0+1)*128];
            float4 a0[4], a1[4], b0[4], b1[4];
            #pragma unroll
            for (int i = 0; i < 4; ++i) {
                a0[i] = *(const float4*)&W0[i*4];
                a1[i] = *(const float4*)&W1[i*4];
            }
            float acc[2][2] = {{0.f,0.f},{0.f,0.f}};
            #pragma unroll
            for (int b = 0; b < 8; ++b) {
                if (b < 7) {
                    #pragma unroll
                    for (int i = 0; i < 4; ++i) {
                        b0[i] = *(const float4*)&W0[(b+1)*16 + i*4];
                        b1[i] = *(const float4*)&W1[(b+1)*16 + i*4];
                    }
                }
                #pragma unroll
                for (int i = 0; i < 4; ++i) {
                    int k4 = b*4 + i;
                    #pragma unroll
                    for (int rr = 0; rr < 2; ++rr) {
                        float4 xv = *(const float4*)&gated[rq*2+rr][128 + k4*4];
                        acc[rr][0] += xv.x*a0[i].x + xv.y*a0[i].y + xv.z*a0[i].z + xv.w*a0[i].w;
                        acc[rr][1] += xv.x*a1[i].x + xv.y*a1[i].y + xv.z*a1[i].z + xv.w*a1[i].w;
                    }
                }
                #pragma unroll
                for (int i = 0; i < 4; ++i) { a0[i] = b0[i]; a1[i] = b1[i]; }
            }
            #pragma unroll
            for (int rr = 0; rr < 2; ++rr) {
                int i = rq*2 + rr, r = row0 + i;
                #pragma unroll
                for (int jj = 0; jj < 2; ++jj) {
                    float v = acc[rr][jj] + mlp_b2[j0+jj];
                    res[i][j0+jj] = v;
                    residual[r*128 + j0 + jj] = v;
                }
            }
        }
    } else {
        for (int idx = tid; idx < 8*256; idx += 256) {
            int i = idx >> 8, dd = idx & 255;
            int r = row0 + i;
            float yv = ybuf[r*256 + dd];
            float zv = xz[r*512 + 256 + dd];
            gated[i][dd] = yv * silu_f(zv);
        }
        __syncthreads();
        {   // out_proj: 2 cols, K=256, batch-8 double-buffered prefetch
            const float* ow = out_proj_w + (size_t)(layer-1)*128*256;
            int jg = tid & 63, rq = tid >> 6;
            int j0 = jg*2;
            const float* W0 = &ow[(size_t)(j0  )*256];
            const float* W1 = &ow[(size_t)(j0+1)*256];
            float4 a0[8], a1[8], b0[8], b1[8];
            #pragma unroll
            for (int i = 0; i < 8; ++i) {
                a0[i] = *(const float4*)&W0[i*4];
                a1[i] = *(const float4*)&W1[i*4];
            }
            float acc[2][2] = {{0.f,0.f},{0.f,0.f}};
            #pragma unroll
            for (int b = 0; b < 8; ++b) {
                if (b < 7) {
                    #pragma unroll
                    for (int i = 0; i < 8; ++i) {
                        b0[i] = *(const float4*)&W0[(b+1)*32 + i*4];
                        b1[i] = *(const float4*)&W1[(b+1)*32 + i*4];
                    }
                }
                #pragma unroll
                for (int i = 0; i < 8; ++i) {
                    int k4 = b*8 + i;
                    #pragma unroll
                    for (int rr = 0; rr < 2; ++rr) {
                        float4 xv = *(const float4*)&gated[rq*2+rr][k4*4];
                        acc[rr][0] += xv.x*a0[i].x + xv.y*a0[i].y + xv.z*a0[i].z + xv.w*a0[i].w;
                        acc[rr][1] += xv.x*a1[i].x + xv.y*a1[i].y + xv.z*a1[i].z + xv.w*a1[i].w;
                    }
                }
                #pragma unroll
                for (int i = 0; i < 8; ++i) { a0[i] = b0[i]; a1[i] = b1[i]; }
            }
            #pragma unroll
            for (int rr = 0; rr < 2; ++rr) {
                int i = rq*2 + rr, r = row0 + i;
                #pragma unroll
                for (int jj = 0; jj < 2; ++jj) {
                    float v = acc[rr][jj] + residual[r*128 + j0 + jj];
                    res[i][j0+jj] = v;
                    residual[r*128 + j0 + jj] = v;
                }
            }
        }
    }
    __syncthreads();

    // rmsnorm
    {
        int r = tid >> 5, lane = tid & 31;
        float sq = 0.f;
        #pragma unroll
        for (int t = 0; t < 4; ++t) { float v = res[r][lane + 32*t]; sq += v*v; }
        part[r][lane] = sq;
    }
    __syncthreads();
    if (tid < 8) {
        float sq = 0.f;
        #pragma unroll
        for (int t = 0; t < 32; ++t) sq += part[tid][t];
        scale[tid] = rsqrtf(sq * (1.0f/128.0f) + 1e-5f);
    }
    __syncthreads();
    {
        const float* bw = blk_norm_w + layer*128;
        for (int idx = tid; idx < 8*128; idx += 256) {
            int i = idx >> 7, c = idx & 127;
            hn[i][c] = res[i][c] * scale[i] * bw[c];
        }
    }
    __syncthreads();

    // in_proj: 4 cols x 4 rows, K=128, batch-4 double-buffered prefetch
    {
        const float* iw = in_proj_w + (size_t)layer*512*128;
        int jg = tid & 127, rh = tid >> 7;
        int j0 = jg*4;
        const float* Wp0 = &iw[(size_t)(j0  )*128];
        const float* Wp1 = &iw[(size_t)(j0+1)*128];
        const float* Wp2 = &iw[(size_t)(j0+2)*128];
        const float* Wp3 = &iw[(size_t)(j0+3)*128];
        float4 wa[4][4], wb[4][4];   // [j][i]
        #pragma unroll
        for (int i = 0; i < 4; ++i) {
            wa[0][i] = *(const float4*)&Wp0[i*4];
            wa[1][i] = *(const float4*)&Wp1[i*4];
            wa[2][i] = *(const float4*)&Wp2[i*4];
            wa[3][i] = *(const float4*)&Wp3[i*4];
        }
        float acc[4][4] = {};
        #pragma unroll
        for (int b = 0; b < 8; ++b) {
            if (b < 7) {
                #pragma unroll
                for (int i = 0; i < 4; ++i) {
                    wb[0][i] = *(const float4*)&Wp0[(b+1)*16 + i*4];
                    wb[1][i] = *(const float4*)&Wp1[(b+1)*16 + i*4];
                    wb[2][i] = *(const float4*)&Wp2[(b+1)*16 + i*4];
                    wb[3][i] = *(const float4*)&Wp3[(b+1)*16 + i*4];
                }
            }
            #pragma unroll
            for (int i = 0; i < 4; ++i) {
                int k4 = b*4 + i;
                #pragma unroll
                for (int rr = 0; rr < 4; ++rr) {
                    float4 xv = *(const float4*)&hn[rh*4+rr][k4*4];
                    #pragma unroll
                    for (int jj = 0; jj < 4; ++jj)
                        acc[rr][jj] += xv.x*wa[jj][i].x + xv.y*wa[jj][i].y
                                     + xv.z*wa[jj][i].z + xv.w*wa[jj][i].w;
                }
            }
            #pragma unroll
            for (int jj = 0; jj < 4; ++jj)
                #pragma unroll
                for (int i = 0; i < 4; ++i) wa[jj][i] = wb[jj][i];
        }
        #pragma unroll
        for (int rr = 0; rr < 4; ++rr) {
            int r = row0 + rh*4 + rr;
            float4 o; o.x = acc[rr][0]; o.y = acc[rr][1]; o.z = acc[rr][2]; o.w = acc[rr][3];
            *(float4*)&xz[r*512 + j0] = o;
        }
    }
}

// ---------------------------------------------------------------------------
// K_BS: 16 wgs x 256 thr. wg (s = bid>>2, db = bid&3) handles sequence s,
// scan channels db*64..+64. conv + x_proj computed redundantly (full 256 ch)
// per wg — cheap (~1.3MF) and avoids cross-wg dependencies.
// ---------------------------------------------------------------------------
__global__ __launch_bounds__(256, 1) void kbs_kernel(
    const float* __restrict__ conv_w, const float* __restrict__ conv_b,
    const float* __restrict__ x_proj_w,
    const float* __restrict__ dt_proj_w, const float* __restrict__ dt_proj_b,
    const float* __restrict__ A_log, const float* __restrict__ D_skip,
    float* __restrict__ ws, int layer)
{
    __shared__ float uS[64][260];    // full 256 ch; stride 260 (4-float pad)
    __shared__ float dtS[64][64];    // own 64 channels
    __shared__ float xdbl[64][44];   // 0..7 dt-pre, 8..23 B, 24..39 C

    float* xz   = ws + WS_XZ;
    float* ybuf = ws + WS_Y;

    const int tid  = threadIdx.x;
    const int s    = blockIdx.x >> 2;
    const int db   = blockIdx.x & 3;
    const int base = s * 64;

    // ---- causal conv (width 4) + silu -> uS (full 256 ch, 1 thr/channel) ----
    {
        const int d = tid;
        const float* cw = conv_w + (size_t)(layer*256 + d)*4;
        float w0 = cw[0], w1 = cw[1], w2 = cw[2], w3 = cw[3];
        float cb = conv_b[layer*256 + d];
        float xm3 = 0.f, xm2 = 0.f, xm1 = 0.f;
        float xa[16], xb[16];
        #pragma unroll
        for (int i = 0; i < 16; ++i) xa[i] = xz[(size_t)(base + i)*512 + d];
        for (int blk = 0; blk < 4; ++blk) {
            if (blk < 3) {
                #pragma unroll
                for (int i = 0; i < 16; ++i)
                    xb[i] = xz[(size_t)(base + (blk+1)*16 + i)*512 + d];
            }
            #pragma unroll
            for (int i = 0; i < 16; ++i) {
                float v = cb + w0*xm3 + w1*xm2 + w2*xm1 + w3*xa[i];
                uS[blk*16 + i][d] = silu_f(v);
                xm3 = xm2; xm2 = xm1; xm1 = xa[i];
            }
            #pragma unroll
            for (int i = 0; i < 16; ++i) xa[i] = xb[i];
        }
    }
    __syncthreads();

    // ---- x_proj (full, redundant): thread = (rgrp, cgrp, q) --------------------
    // rgrp = tid>>4 (4 rows each), cgrp = (tid>>2)&3 (10 cols), q = tid&3
    // (K-quarter, 16 k4 each). Weights double-buffered from global.
    {
        const int rgrp = tid >> 4, cgrp = (tid >> 2) & 3, q = tid & 3;
        const int r0 = rgrp * 4, c0 = cgrp * 10;
        const float* xw = x_proj_w + (size_t)layer*40*256;
        float4 wcur[10], wnxt[10];
        #pragma unroll
        for (int j = 0; j < 10; ++j)
            wcur[j] = *(const float4*)&xw[(size_t)(c0+j)*256 + (q*16)*4];
        float acc[4][10] = {};
        #pragma unroll
        for (int kk = 0; kk < 16; ++kk) {
            int k4 = q*16 + kk;
            if (kk < 15) {
                #pragma unroll
                for (int j = 0; j < 10; ++j)
                    wnxt[j] = *(const float4*)&xw[(size_t)(c0+j)*256 + (k4+1)*4];
            }
            float4 u[4];
            #pragma unroll
            for (int rr = 0; rr < 4; ++rr)
                u[rr] = *(const float4*)&uS[r0+rr][k4*4];
            #pragma unroll
            for (int rr = 0; rr < 4; ++rr)
                #pragma unroll
                for (int j = 0; j < 10; ++j)
                    acc[rr][j] += u[rr].x*wcur[j].x + u[rr].y*wcur[j].y
                                + u[rr].z*wcur[j].z + u[rr].w*wcur[j].w;
            #pragma unroll
            for (int j = 0; j < 10; ++j) wcur[j] = wnxt[j];
        }
        // combine K-quarters across q (lane bits 0,1)
        #pragma unroll
        for (int rr = 0; rr < 4; ++rr)
            #pragma unroll
            for (int j = 0; j < 10; ++j) {
                float v = acc[rr][j];
                v += __shfl_xor(v, 1);
                v += __shfl_xor(v, 2);
                if (q == 0) xdbl[r0+rr][c0+j] = v;
            }
    }
    __syncthreads();

    // ---- dt = softplus(xdbl[:,:8] @ dtw^T + dtb) for own 64 channels ----
    {
        const int ch = tid & 63;           // own-channel index
        const int lbase = (tid >> 6) * 16;
        const float* dw = dt_proj_w + (size_t)(layer*256 + db*64 + ch)*8;
        float4 w0 = *(const float4*)&dw[0];
        float4 w1 = *(const float4*)&dw[4];
        float bdt = dt_proj_b[layer*256 + db*64 + ch];
        #pragma unroll
        for (int i = 0; i < 16; ++i) {
            int l = lbase + i;
            float pre = bdt
                + xdbl[l][0]*w0.x + xdbl[l][1]*w0.y + xdbl[l][2]*w0.z + xdbl[l][3]*w0.w
                + xdbl[l][4]*w1.x + xdbl[l][5]*w1.y + xdbl[l][6]*w1.z + xdbl[l][7]*w1.w;
            dtS[l][ch] = (pre > 20.f) ? pre : __logf(1.0f + __expf(pre));
        }
    }
    __syncthreads();

    // ---- selective scan: own 64 channels, 4 thr/channel, dA precomputed ----
    {
        const int dloc = tid >> 2, sub = tid & 3;
        const int d = db*64 + dloc;
        float A[4], h[4] = {0.f,0.f,0.f,0.f};
        #pragma unroll
        for (int j = 0; j < 4; ++j)
            A[j] = -__expf(A_log[(size_t)(layer*256 + d)*16 + sub*4 + j]);
        float Dsk = D_skip[layer*256 + d];

        float dtv = dtS[0][dloc];
        float uv  = uS[0][d];
        float4 B4 = *(const float4*)&xdbl[0][ 8 + sub*4];
        float4 C4 = *(const float4*)&xdbl[0][24 + sub*4];
        float dA0 = __expf(dtv*A[0]), dA1 = __expf(dtv*A[1]);
        float dA2 = __expf(dtv*A[2]), dA3 = __expf(dtv*A[3]);

        for (int l = 0; l < 64; ++l) {
            float dtn = 0.f, un = 0.f; float4 Bn = {0,0,0,0}, Cn = {0,0,0,0};
            float dAn0 = 0.f, dAn1 = 0.f, dAn2 = 0.f, dAn3 = 0.f;
            if (l < 63) {
                dtn = dtS[l+1][dloc];
                un  = uS[l+1][d];
                Bn  = *(const float4*)&xdbl[l+1][ 8 + sub*4];
                Cn  = *(const float4*)&xdbl[l+1][24 + sub*4];
                dAn0 = __expf(dtn*A[0]); dAn1 = __expf(dtn*A[1]);
                dAn2 = __expf(dtn*A[2]); dAn3 = __expf(dtn*A[3]);
            }
            float du = dtv * uv;
            float yp = 0.f;
            h[0] = dA0*h[0] + du*B4.x; yp += h[0]*C4.x;
            h[1] = dA1*h[1] + du*B4.y; yp += h[1]*C4.y;
            h[2] = dA2*h[2] + du*B4.z; yp += h[2]*C4.z;
            h[3] = dA3*h[3] + du*B4.w; yp += h[3]*C4.w;
            yp += __shfl_xor(yp, 1);
            yp += __shfl_xor(yp, 2);
            if (sub == 0) ybuf[(size_t)(base + l)*256 + d] = yp + uv*Dsk;
            dtv = dtn; uv = un; B4 = Bn; C4 = Cn;
            dA0 = dAn0; dA1 = dAn1; dA2 = dAn2; dA3 = dAn3;
        }
    }
}

// ---------------------------------------------------------------------------
// kfin: last-layer gate + out_proj (row l=63) + residual + rmsnorm + mask.
// 4 wgs x 256 thr, one sequence each.
// ---------------------------------------------------------------------------
__global__ __launch_bounds__(256, 1) void kfin_kernel(
    const float* __restrict__ out_proj_w, const float* __restrict__ norm_f_w,
    const int* __restrict__ mask,
    float* __restrict__ ws, float* __restrict__ out)
{
    __shared__ float fing[256];
    __shared__ float finpart[2][128];
    __shared__ float finred[2];
    __shared__ float validf;

    float* residual = ws + WS_RESIDUAL;
    float* xz       = ws + WS_XZ;
    float* ybuf     = ws + WS_Y;

    const int tid = threadIdx.x;
    const int s   = blockIdx.x;
    const int row = s*64 + 63;

    fing[tid] = ybuf[(size_t)row*256 + tid] * silu_f(xz[(size_t)row*512 + 256 + tid]);
    if (tid < 64) {
        unsigned long long b = __ballot(mask[s*4096 + tid] != 0);
        if (tid == 0) validf = (b != 0ULL) ? 1.f : 0.f;
    }
    __syncthreads();
    {
        int j = tid & 127, kh = tid >> 7;        // K halves of 128
        const float* W = out_proj_w + (size_t)3*128*256 + (size_t)j*256 + kh*128;
        float4 a[8], b[8];
        #pragma unroll
        for (int i = 0; i < 8; ++i) a[i] = *(const float4*)&W[i*4];
        float acc = 0.f;
        #pragma unroll
        for (int blk = 0; blk < 4; ++blk) {
            if (blk < 3) {
                #pragma unroll
                for (int i = 0; i < 8; ++i) b[i] = *(const float4*)&W[(blk+1)*32 + i*4];
            }
            #pragma unroll
            for (int i = 0; i < 8; ++i) {
                float4 g = *(const float4*)&fing[kh*128 + blk*32 + i*4];
                acc += g.x*a[i].x + g.y*a[i].y + g.z*a[i].z + g.w*a[i].w;
            }
            #pragma unroll
            for (int i = 0; i < 8; ++i) a[i] = b[i];
        }
        finpart[kh][j] = acc;
    }
    __syncthreads();
    float v = 0.f;
    if (tid < 128)
        v = finpart[0][tid] + finpart[1][tid] + residual[(size_t)row*128 + tid];
    float p = v * v;
    p += __shfl_xor(p, 1);  p += __shfl_xor(p, 2);  p += __shfl_xor(p, 4);
    p += __shfl_xor(p, 8);  p += __shfl_xor(p, 16); p += __shfl_xor(p, 32);
    if (tid < 128 && (tid & 63) == 0) finred[tid >> 6] = p;
    __syncthreads();
    if (tid < 128) {
        float tot = finred[0] + finred[1];
        out[s*128 + tid] = v * rsqrtf(tot * (1.0f/128.0f) + 1e-5f)
                         * norm_f_w[tid] * validf;
    }
}

// ---------------------------------------------------------------------------
extern "C" void kernel_launch(void* const* d_in, const int* in_sizes, int n_in,
                              void* d_out, int out_size, void* d_ws, size_t ws_size,
                              hipStream_t stream) {
    const float* mha_in     = (const float*)d_in[0];
    const int*   mask       = (const int*)  d_in[1];
    const float* mlp_w1     = (const float*)d_in[2];
    const float* mlp_b1     = (const float*)d_in[3];
    const float* mlp_w2     = (const float*)d_in[4];
    const float* mlp_b2     = (const float*)d_in[5];
    const float* in_proj_w  = (const float*)d_in[6];
    const float* conv_w     = (const float*)d_in[7];
    const float* conv_b     = (const float*)d_in[8];
    const float* x_proj_w   = (const float*)d_in[9];
    const float* dt_proj_w  = (const float*)d_in[10];
    const float* dt_proj_b  = (const float*)d_in[11];
    const float* A_log      = (const float*)d_in[12];
    const float* D_skip     = (const float*)d_in[13];
    const float* out_proj_w = (const float*)d_in[14];
    const float* blk_norm_w = (const float*)d_in[15];
    const float* norm_f_w   = (const float*)d_in[16];
    float* ws  = (float*)d_ws;
    float* out = (float*)d_out;

    for (int layer = 0; layer < 4; ++layer) {
        ka_kernel<<<32, 256, 0, stream>>>(mha_in, mlp_w1, mlp_b1, mlp_w2, mlp_b2,
                                          in_proj_w, out_proj_w, blk_norm_w, ws, layer);
        kbs_kernel<<<16, 256, 0, stream>>>(conv_w, conv_b, x_proj_w,
                                           dt_proj_w, dt_proj_b, A_log, D_skip,
                                           ws, layer);
    }
    kfin_kernel<<<4, 256, 0, stream>>>(out_proj_w, norm_f_w, mask, ws, out);
}